// Round 8
// baseline (761.804 us; speedup 1.0000x reference)
//
#include <hip/hip_runtime.h>
#include <hip/hip_bf16.h>
#include <stdint.h>

// Int8Linear: y[m,n] = scale[n] * sum_k x[m,k]*w[n,k] + bias[n]
// Device dtypes: x fp32 [8192,4096]; w int32 [11008,4096] (|v|<=127);
// scale/bias fp32 [11008]; out fp32 [8192,11008].
// Round 8: same 256x256 BK=64 dbuf-2 GEMM as round 7 but with the inner tile
// UN-PINNED: one barrier per K-tile, no per-phase lgkmcnt(0)/sched_barrier
// around MFMA (the m141 order-pinning pathology measured as pipe
// serialization: r7 tile time == LDS-pipe + MFMA-pipe SUM). Compiler now
// free-schedules ds_read <-> MFMA with counted lgkmcnt. Staging issue pinned
// before compute by a single sched_barrier(0). setprio removed (ordered
// intrinsic == re-fencing). All validated pieces unchanged: XOR bank swizzle,
// staging addressing, epilogue layout, prepass, XCD swizzle.

#define K_DIM 4096
#define N_DIM 11008
#define M_DIM 8192

typedef __attribute__((ext_vector_type(8))) __bf16 bf16x8;
typedef __attribute__((ext_vector_type(4))) float f32x4;
typedef __attribute__((ext_vector_type(4))) int i32x4;

#define SB0 __builtin_amdgcn_sched_barrier(0)

__device__ __forceinline__ void gload_lds16(const void* g, void* l) {
  __builtin_amdgcn_global_load_lds(
      (const __attribute__((address_space(1))) void*)g,
      (__attribute__((address_space(3))) void*)l, 16, 0, 0);
}

// ---------------- prepass conversions (validated round 3) ----------------

__global__ void __launch_bounds__(256) wconv_kernel(const int* __restrict__ w,
                                                    __bf16* __restrict__ o,
                                                    int n8) {
  int i = blockIdx.x * 256 + threadIdx.x;
  if (i >= n8) return;
  const i32x4* src = (const i32x4*)w;
  i32x4 v0 = src[2 * i];
  i32x4 v1 = src[2 * i + 1];
  bf16x8 r;
#pragma unroll
  for (int j = 0; j < 4; ++j) {
    r[j]     = (__bf16)(float)v0[j];
    r[j + 4] = (__bf16)(float)v1[j];
  }
  *((bf16x8*)o + i) = r;
}

__global__ void __launch_bounds__(256) xconv_kernel(const float* __restrict__ x,
                                                    __bf16* __restrict__ o,
                                                    int n8) {
  int i = blockIdx.x * 256 + threadIdx.x;
  if (i >= n8) return;
  const f32x4* src = (const f32x4*)x;
  f32x4 v0 = src[2 * i];
  f32x4 v1 = src[2 * i + 1];
  bf16x8 r;
#pragma unroll
  for (int j = 0; j < 4; ++j) {
    r[j]     = (__bf16)v0[j];
    r[j + 4] = (__bf16)v1[j];
  }
  *((bf16x8*)o + i) = r;
}

// ---------------- 256x256 BK=64 GEMM, 1 barrier/tile ----------------

#define BM 256
#define BN 256
#define BK 64
#define KT (K_DIM / BK)  /* 64 */
#define MT (M_DIM / BM)  /* 32 */
#define NT (N_DIM / BN)  /* 43 */
#define NBLK (MT * NT)   /* 1376 = 8*172 */
#define ABUF 16384       /* elems: one operand tile 256x64 */
#define BUFSZ 32768      /* elems: A+B per buffer = 64 KiB */

__global__ void __launch_bounds__(512, 2) gemm256_kernel(
    const __bf16* __restrict__ Xb, const __bf16* __restrict__ Wb,
    const float* __restrict__ scale, const float* __restrict__ bias,
    float* __restrict__ out) {
  __shared__ __align__(16) __bf16 lds[2 * BUFSZ];  // 128 KiB

  const int tid = threadIdx.x;
  const int lane = tid & 63;
  const int wv = tid >> 6;  // 0..7
  const int wr = wv >> 2;   // 0..1 (M half: 128 rows)
  const int wc = wv & 3;    // 0..3 (N quarter: 64 cols)

  // T1: bijective XCD swizzle (1376 = 8*172)
  const int lid = blockIdx.x;
  const int swz = (lid & 7) * (NBLK / 8) + (lid >> 3);
  const int tm = swz / NT;
  const int tn = swz - tm * NT;
  const size_t m0 = (size_t)tm * BM;
  const size_t n0 = (size_t)tn * BN;

  // staging: wave wv covers rows [R0+wv*8, R0+wv*8+8), 8 x 16B slots/row.
  // LDS[R][s] holds global k-chunk (s ^ (R&7)): inverse-swizzled global
  // source + wave-uniform LDS base (HW writes lane i at base + i*16B).
  const int srow = tid >> 3;  // 0..63 (= wv*8 + (lane>>3))
  const int gchunk = (tid & 7) ^ (srow & 7);
  const size_t gOff = (size_t)srow * K_DIM + gchunk * 8;
  const int ldsWv = wv * 512;  // wave-uniform elem offset
  const __bf16* GA = Xb + m0 * K_DIM;
  const __bf16* GB = Wb + n0 * K_DIM;

#define STG(LP, OPB, R0, G, TS)                                      \
  gload_lds16((G) + (size_t)(R0) * K_DIM + (size_t)(TS) * BK + gOff, \
              &lds[(LP) * BUFSZ + (OPB) + (R0) * 64 + ldsWv])

  // fragment read addressing (swizzled): slot = (ks*4+kg) ^ (fr&7)
  const int fr = lane & 15;
  const int kg = lane >> 4;
  const int sw = fr & 7;
  const int aBase = (wr * 128 + fr) * 64;
  const int bBase = ABUF + (wc * 64 + fr) * 64;
  const int s0 = ((0 * 4 + kg) ^ sw) * 8;
  const int s1 = ((1 * 4 + kg) ^ sw) * 8;

#define RDA(LP, RF, KS) \
  (*(const bf16x8*)&lds[(LP)*BUFSZ + aBase + (RF)*1024 + ((KS) ? s1 : s0)])
#define RDB(LP, CF, KS) \
  (*(const bf16x8*)&lds[(LP)*BUFSZ + bBase + (CF)*1024 + ((KS) ? s1 : s0)])

  f32x4 acc[8][4];
#pragma unroll
  for (int m = 0; m < 8; ++m)
#pragma unroll
    for (int n = 0; n < 4; ++n) acc[m][n] = (f32x4){0.f, 0.f, 0.f, 0.f};

  // ---- prologue: stage tile 0 into buffer 0; drain; barrier ----
  STG(0, 0, 0, GA, 0);      STG(0, 0, 64, GA, 0);
  STG(0, 0, 128, GA, 0);    STG(0, 0, 192, GA, 0);
  STG(0, ABUF, 0, GB, 0);   STG(0, ABUF, 64, GB, 0);
  STG(0, ABUF, 128, GB, 0); STG(0, ABUF, 192, GB, 0);
  asm volatile("s_waitcnt vmcnt(0)" ::: "memory");
  SB0;
  __builtin_amdgcn_s_barrier();

  for (int t = 0; t < KT; ++t) {
    const int p = t & 1;
    const int np = p ^ 1;

    // 1) issue next-tile staging first (8 DMAs); pin issue-before-compute.
    if (t + 1 < KT) {
      STG(np, 0, 0, GA, t + 1);      STG(np, 0, 64, GA, t + 1);
      STG(np, 0, 128, GA, t + 1);    STG(np, 0, 192, GA, t + 1);
      STG(np, ABUF, 0, GB, t + 1);   STG(np, ABUF, 64, GB, t + 1);
      STG(np, ABUF, 128, GB, t + 1); STG(np, ABUF, 192, GB, t + 1);
    }
    SB0;

    // 2) compute tile t from buffer p — plain code, compiler-scheduled.
    bf16x8 b0[4], b1[4];
#pragma unroll
    for (int nf = 0; nf < 4; ++nf) {
      b0[nf] = RDB(p, nf, 0);
      b1[nf] = RDB(p, nf, 1);
    }
#pragma unroll
    for (int mf = 0; mf < 8; ++mf) {
      bf16x8 a0 = RDA(p, mf, 0);
      bf16x8 a1 = RDA(p, mf, 1);
#pragma unroll
      for (int nf = 0; nf < 4; ++nf) {
        acc[mf][nf] = __builtin_amdgcn_mfma_f32_16x16x32_bf16(
            a0, b0[nf], acc[mf][nf], 0, 0, 0);
        acc[mf][nf] = __builtin_amdgcn_mfma_f32_16x16x32_bf16(
            a1, b1[nf], acc[mf][nf], 0, 0, 0);
      }
    }

    // 3) tile end: reads of p consumed (lgkm free), tile t+1 landed (vmcnt
    //    hidden under ~2400 cyc of compute), then the single barrier.
    asm volatile("s_waitcnt lgkmcnt(0)" ::: "memory");
    asm volatile("s_waitcnt vmcnt(0)" ::: "memory");
    __builtin_amdgcn_s_barrier();
  }

  // ---- epilogue: C/D layout col=lane&15, row=(lane>>4)*4+reg ----
  const int cc = lane & 15;
  const int rr = (lane >> 4) * 4;
#pragma unroll
  for (int nf = 0; nf < 4; ++nf) {
    const int col = (int)n0 + wc * 64 + nf * 16 + cc;
    const float sc = scale[col];
    const float bi = bias[col];
#pragma unroll
    for (int mf = 0; mf < 8; ++mf) {
      const size_t rowb = m0 + wr * 128 + mf * 16 + rr;
#pragma unroll
      for (int r = 0; r < 4; ++r) {
        out[(rowb + r) * N_DIM + col] = acc[mf][nf][r] * sc + bi;
      }
    }
  }
#undef STG
#undef RDA
#undef RDB
}

// ---------------- fallback 128x128 kernel (round-3 validated) ----------------

#define FBM 128
#define FBN 128
#define FBK 32
#define FNT (N_DIM / FBN) /* 86 */
#define FMT (M_DIM / FBM) /* 64 */

__device__ __forceinline__ bf16x8 cvt8f(f32x4 a, f32x4 b) {
  bf16x8 h;
#pragma unroll
  for (int j = 0; j < 4; ++j) {
    h[j] = (__bf16)a[j];
    h[j + 4] = (__bf16)b[j];
  }
  return h;
}

__device__ __forceinline__ bf16x8 cvt8i(i32x4 a, i32x4 b) {
  bf16x8 h;
#pragma unroll
  for (int j = 0; j < 4; ++j) {
    h[j] = (__bf16)(float)a[j];
    h[j + 4] = (__bf16)(float)b[j];
  }
  return h;
}

template <int MODE>  // 1: W preconv; 2: no workspace
__global__ void __launch_bounds__(256, 2) gemm_fb_kernel(
    const float* __restrict__ X, const __bf16* __restrict__ Wb,
    const int* __restrict__ Wq, const float* __restrict__ scale,
    const float* __restrict__ bias, float* __restrict__ out) {
  __shared__ __align__(16) __bf16 As[FBM * FBK];
  __shared__ __align__(16) __bf16 Bs[FBN * FBK];

  const int tid = threadIdx.x;
  const int lane = tid & 63;
  const int wv = tid >> 6;

  const int lid = blockIdx.x;
  const int swz = (lid & 7) * ((FMT * FNT) >> 3) + (lid >> 3);
  const int tm = swz / FNT;
  const int tn = swz - tm * FNT;
  const int m0 = tm * FBM;
  const int n0 = tn * FBN;

  const int e0 = wv * 512 + lane * 8;
  const int e1 = e0 + 2048;
  const int r0 = e0 >> 5, c0 = e0 & 31;
  const int r1 = e1 >> 5, c1 = e1 & 31;

  f32x4 acc[4][4];
#pragma unroll
  for (int m = 0; m < 4; ++m)
#pragma unroll
    for (int n = 0; n < 4; ++n) acc[m][n] = (f32x4){0.f, 0.f, 0.f, 0.f};

  const int wm = (wv >> 1) * 64;
  const int wn = (wv & 1) * 64;
  const int fr = lane & 15;
  const int kc = (lane >> 4) * 8;

  const float* srcAf0 = X + (size_t)(m0 + r0) * K_DIM + c0;
  const float* srcAf1 = X + (size_t)(m0 + r1) * K_DIM + c1;
  const __bf16* srcBb0 = Wb + (size_t)(n0 + r0) * K_DIM + c0;
  const __bf16* srcBb1 = Wb + (size_t)(n0 + r1) * K_DIM + c1;
  const int* srcQ0 = Wq + (size_t)(n0 + r0) * K_DIM + c0;
  const int* srcQ1 = Wq + (size_t)(n0 + r1) * K_DIM + c1;

  for (int k0 = 0; k0 < K_DIM; k0 += FBK) {
    f32x4 a0 = *(const f32x4*)(srcAf0 + k0);
    f32x4 a1 = *(const f32x4*)(srcAf0 + k0 + 4);
    f32x4 a2 = *(const f32x4*)(srcAf1 + k0);
    f32x4 a3 = *(const f32x4*)(srcAf1 + k0 + 4);
    if constexpr (MODE == 1) {
      gload_lds16(srcBb0 + k0, &Bs[e0]);
      gload_lds16(srcBb1 + k0, &Bs[e1]);
    } else {
      i32x4 q0 = *(const i32x4*)(srcQ0 + k0);
      i32x4 q1 = *(const i32x4*)(srcQ0 + k0 + 4);
      i32x4 q2 = *(const i32x4*)(srcQ1 + k0);
      i32x4 q3 = *(const i32x4*)(srcQ1 + k0 + 4);
      *(bf16x8*)&Bs[e0] = cvt8i(q0, q1);
      *(bf16x8*)&Bs[e1] = cvt8i(q2, q3);
    }
    *(bf16x8*)&As[e0] = cvt8f(a0, a1);
    *(bf16x8*)&As[e1] = cvt8f(a2, a3);
    __syncthreads();

    bf16x8 a[4], b[4];
#pragma unroll
    for (int m = 0; m < 4; ++m)
      a[m] = *(const bf16x8*)&As[(wm + m * 16 + fr) * FBK + kc];
#pragma unroll
    for (int n = 0; n < 4; ++n)
      b[n] = *(const bf16x8*)&Bs[(wn + n * 16 + fr) * FBK + kc];
#pragma unroll
    for (int m = 0; m < 4; ++m)
#pragma unroll
      for (int n = 0; n < 4; ++n)
        acc[m][n] = __builtin_amdgcn_mfma_f32_16x16x32_bf16(a[m], b[n],
                                                            acc[m][n], 0, 0, 0);
    __syncthreads();
  }

  const int cc = lane & 15;
  const int rr = (lane >> 4) * 4;
#pragma unroll
  for (int n = 0; n < 4; ++n) {
    const int col = n0 + wn + n * 16 + cc;
    const float sc = scale[col];
    const float bi = bias[col];
#pragma unroll
    for (int m = 0; m < 4; ++m) {
      const int rowb = m0 + wm + m * 16 + rr;
#pragma unroll
      for (int r = 0; r < 4; ++r) {
        out[(size_t)(rowb + r) * N_DIM + col] = acc[m][n][r] * sc + bi;
      }
    }
  }
}

// ---------------- launch ----------------

extern "C" void kernel_launch(void* const* d_in, const int* in_sizes, int n_in,
                              void* d_out, int out_size, void* d_ws, size_t ws_size,
                              hipStream_t stream) {
  const float* X = (const float*)d_in[0];
  const int* Wq = (const int*)d_in[1];
  const float* scale = (const float*)d_in[2];
  const float* bias = (const float*)d_in[3];
  float* out = (float*)d_out;

  const size_t wbytes = (size_t)N_DIM * K_DIM * sizeof(__bf16);  // 90,177,536
  const size_t xbytes = (size_t)M_DIM * K_DIM * sizeof(__bf16);  // 67,108,864
  const int n8w = (N_DIM * K_DIM) / 8;
  const int n8x = (M_DIM * K_DIM) / 8;

  if (ws_size >= wbytes + xbytes) {
    __bf16* Wb = (__bf16*)d_ws;
    __bf16* Xb = (__bf16*)((char*)d_ws + wbytes);
    wconv_kernel<<<dim3((n8w + 255) / 256), dim3(256), 0, stream>>>(Wq, Wb, n8w);
    xconv_kernel<<<dim3((n8x + 255) / 256), dim3(256), 0, stream>>>(X, Xb, n8x);
    gemm256_kernel<<<dim3(NBLK), dim3(512), 0, stream>>>(Xb, Wb, scale, bias, out);
  } else if (ws_size >= wbytes) {
    __bf16* Wb = (__bf16*)d_ws;
    wconv_kernel<<<dim3((n8w + 255) / 256), dim3(256), 0, stream>>>(Wq, Wb, n8w);
    gemm_fb_kernel<1><<<dim3(FMT * FNT), dim3(256), 0, stream>>>(
        X, Wb, Wq, scale, bias, out);
  } else {
    gemm_fb_kernel<2><<<dim3(FMT * FNT), dim3(256), 0, stream>>>(
        X, nullptr, Wq, scale, bias, out);
  }
}